// Round 18
// baseline (31.140 us; speedup 1.0000x reference)
//
#include <hip/hip_runtime.h>

#define NROWS 8192
#define DIM 128
#define NT 64      // 128x128 tiles per side; flat triangular list has 2080
#define NBLK 512   // pairwise blocks; each owns exactly 4 tiles (+1 strip/4)

typedef _Float16 f16x8 __attribute__((ext_vector_type(8)));
typedef _Float16 f16x4 __attribute__((ext_vector_type(4)));
typedef float f32x16 __attribute__((ext_vector_type(16)));

#define L2E 1.4426950408889634f      // log2(e)
#define SQRTL2E 1.2011224087864498f  // sqrt(log2(e))

#define AS1(p) ((const __attribute__((address_space(1))) void*)(p))
#define AS3(p) ((__attribute__((address_space(3))) void*)(p))

// ---------------------------------------------------------------------------
// Kernel 1: per-row L2 normalize (fp32, as reference), float4-vectorized,
// zh pre-scaled by sqrt(log2e) (R17-verified: Gram MFMA then yields L2E*dot
// and the -L2E constant rides the MFMA C-input). 256 blocks x 32 rows.
// ---------------------------------------------------------------------------
__global__ __launch_bounds__(1024) void fmicl_normalize(
    const float* __restrict__ z1, const float* __restrict__ z2,
    _Float16* __restrict__ zh, float* __restrict__ sposB) {
  const int wid = threadIdx.x >> 6;
  const int lane = threadIdx.x & 63;
  const int half = lane >> 5;   // 0/1: which of the wave's two rows
  const int li = lane & 31;     // position within the row (x float4)
  const int row = blockIdx.x * 32 + wid * 2 + half;

  const float4 a = ((const float4*)(z1 + (size_t)row * DIM))[li];
  const float4 b = ((const float4*)(z2 + (size_t)row * DIM))[li];
  float s1 = a.x * a.x + a.y * a.y + a.z * a.z + a.w * a.w;
  float s2 = b.x * b.x + b.y * b.y + b.z * b.z + b.w * b.w;
#pragma unroll
  for (int off = 16; off; off >>= 1) {  // within-half reduction (32 lanes)
    s1 += __shfl_xor(s1, off);
    s2 += __shfl_xor(s2, off);
  }
  const float inv1 = 1.0f / fmaxf(sqrtf(s1), 1e-12f);
  const float inv2 = 1.0f / fmaxf(sqrtf(s2), 1e-12f);
  const float n1x = a.x * inv1, n1y = a.y * inv1, n1z = a.z * inv1,
              n1w = a.w * inv1;
  const float dx = n1x - b.x * inv2, dy = n1y - b.y * inv2,
              dz = n1z - b.z * inv2, dw = n1w - b.w * inv2;
  float dp = dx * dx + dy * dy + dz * dz + dw * dw;
#pragma unroll
  for (int off = 16; off; off >>= 1) dp += __shfl_xor(dp, off);

  f16x4 h;  // store n1 * sqrt(log2e)
  h.x = (_Float16)(n1x * SQRTL2E);
  h.y = (_Float16)(n1y * SQRTL2E);
  h.z = (_Float16)(n1z * SQRTL2E);
  h.w = (_Float16)(n1w * SQRTL2E);
  *(f16x4*)(zh + (size_t)row * DIM + 4 * li) = h;

  __shared__ float sposL[32];
  if (li == 0)
    sposL[wid * 2 + half] = logf(expf(-0.5f * dp) + 1e-8f) + 1.0f;  // f'(g_pos)
  __syncthreads();
  if (threadIdx.x == 0) {
    float s = 0.0f;
#pragma unroll
    for (int k = 0; k < 32; ++k) s += sposL[k];
    sposB[blockIdx.x] = s;
  }
}

// ---------------------------------------------------------------------------
// Stage one 128-row B panel (32 KiB) into LDS via global_load_lds width=16.
// LDS dest linear; global source pre-swizzled (granule col ^= row&15);
// read side applies the same XOR (involution; rounds 3-17 verified,
// 0 bank conflicts). 4 VMEM instructions per wave.
// ---------------------------------------------------------------------------
__device__ __forceinline__ void stageB(const _Float16* __restrict__ zh,
                                       _Float16* buf, int ct, int wid,
                                       int lane) {
  const _Float16* base = zh + ((size_t)ct << 7) * DIM;
#pragma unroll
  for (int it = 0; it < 4; ++it) {
    const int P = it * 8 + wid;          // wave-uniform 4-row group 0..31
    const int R = P * 4 + (lane >> 4);   // row 0..127
    const int cs = (lane & 15) ^ (R & 15);
    __builtin_amdgcn_global_load_lds(AS1(base + (size_t)R * DIM + cs * 8),
                                     AS3(buf + P * 512), 16, 0, 0);
  }
}

// decode flat triangular index -> (rt, ct); C(r) = r*NT - r(r-1)/2
__device__ __forceinline__ void triDecode(int idx, int& rt, int& ct) {
  int r = (int)(64.5f - sqrtf(64.5f * 64.5f - 2.0f * (float)idx));
  if (r < 0) r = 0;
  while (r > 0 && (r * NT - (r * (r - 1)) / 2) > idx) --r;
  while (((r + 1) * NT - ((r + 1) * r) / 2) <= idx) ++r;
  rt = r;
  ct = r + (idx - (r * NT - (r * (r - 1)) / 2));
}

// ---------------------------------------------------------------------------
// Kernel 2: champion pairwise (R17 pipeline) + BALANCED work split.
// 2080 tiles don't divide by 512: the old len-5 scheme left a ~3.4 us tail
// where only 32 blocks ran a 5th tile. NEW: every block runs exactly 4 tiles
// (flat list 0..2047); the last 32 tiles are split into 128 column-strips of
// 128x32 (4/tile), one strip per block with c%4==0 as a short post-loop
// phase (4 waves x one 32x32 chain, A/B frags global->reg, ~0.3-0.5 us).
// Main loop per tile: 8 waves (4M x 2N), 32 A-rows in regs x 64 B-cols from
// LDS (2 ds_read_b128 -> 2 MFMA per K-step), B dbuf 2x32 KiB, counted
// vmcnt(4) (T4), acc init -L2E, epilogue gsum += exp2(acc[r]) (2 ops/pair).
// XCD swizzle (bid&7)*64+bid>>3 (bijective). No atomics.
// ---------------------------------------------------------------------------
__global__ __launch_bounds__(512, 4) void fmicl_pairwise(
    const _Float16* __restrict__ zh, float* __restrict__ pairP) {
  __shared__ _Float16 B0[128 * DIM];  // 32 KiB
  __shared__ _Float16 B1[128 * DIM];  // 32 KiB
  __shared__ float wsum[8];

  const int tid = threadIdx.x;
  const int lane = tid & 63;
  const int wid = tid >> 6;
  const int l31 = lane & 31;
  const int lhi = lane >> 5;
  const int m = wid >> 1;  // 0..3: 32-row block of the band
  const int n = wid & 1;   // 0..1: 64-col half of the tile

  // XCD-chunked swizzle (512 = 8*64, bijective; 256 main tiles per XCD)
  const int c = (blockIdx.x & 7) * 64 + (blockIdx.x >> 3);
  const int base = 4 * c;  // tiles [4c, 4c+4) of the first 2048

  int rtt, ctt;
  triDecode(base, rtt, ctt);

  stageB(zh, B0, ctt, wid, lane);  // prologue stage of tile 0

  uint4 areg[8];
  int cur_rt = -1;
  float gsum = 0.0f;

#pragma unroll 1
  for (int t = 0; t < 4; ++t) {
    // ---- A-regs: reload only on band crossing ----
    if (rtt != cur_rt) {
      cur_rt = rtt;
      const uint4* ar =
          (const uint4*)(zh + (size_t)((rtt << 7) + m * 32 + l31) * DIM);
#pragma unroll
      for (int ks = 0; ks < 8; ++ks) areg[ks] = ar[2 * ks + lhi];
    }
    // ---- next tile coords; issue its stage before computing this one ----
    int nrt = rtt, nct = ctt + 1;
    if (nct == NT) { ++nrt; nct = nrt; }
    if (t + 1 < 4) {
      stageB(zh, (t & 1) ? B0 : B1, nct, wid, lane);
      // all but the newest 4 loads (= next tile's stage) complete
      asm volatile("s_waitcnt vmcnt(4)" ::: "memory");
    } else {
      asm volatile("s_waitcnt vmcnt(0)" ::: "memory");
    }
    __builtin_amdgcn_s_barrier();
    __builtin_amdgcn_sched_barrier(0);

    // ---- compute: 8 K-steps, 2 B-reads -> 2 MFMA; acc starts at -L2E ----
    const uint4* B4 = (const uint4*)((t & 1) ? B1 : B0);
    const int rb0 = n * 64 + l31;
    const int rb1 = n * 64 + 32 + l31;
    f32x16 acc0, acc1;
#pragma unroll
    for (int r = 0; r < 16; ++r) {
      acc0[r] = -L2E;
      acc1[r] = -L2E;
    }
#pragma unroll
    for (int ks = 0; ks < 8; ++ks) {
      const int kg = 2 * ks + lhi;
      const uint4 vb0 = B4[rb0 * 16 + (kg ^ (rb0 & 15))];
      const uint4 vb1 = B4[rb1 * 16 + (kg ^ (rb1 & 15))];
      const f16x8 af = __builtin_bit_cast(f16x8, areg[ks]);
      acc0 = __builtin_amdgcn_mfma_f32_32x32x16_f16(
          af, __builtin_bit_cast(f16x8, vb0), acc0, 0, 0, 0);
      acc1 = __builtin_amdgcn_mfma_f32_32x32x16_f16(
          af, __builtin_bit_cast(f16x8, vb1), acc1, 0, 0, 0);
    }

    // ---- epilogue: g = exp2(acc[r]) == exp(dot-1) == exp(-d2/2) ----
    // C/D layout (32x32): col=lane&31, row=(reg&3)+8*(reg>>2)+4*(lane>>5)
    float tsum0 = 0.0f, tsum1 = 0.0f;
    const bool dsub0 = (rtt == ctt) && (m == 2 * n);      // chain-0 diag
    const bool dsub1 = (rtt == ctt) && (m == 2 * n + 1);  // chain-1 diag
    if (dsub0 || dsub1) {
#pragma unroll
      for (int r = 0; r < 16; ++r) {
        const float e0 = __builtin_amdgcn_exp2f(acc0[r]);
        const float e1 = __builtin_amdgcn_exp2f(acc1[r]);
        const int mloc = (r & 3) + 4 * lhi + 8 * (r >> 2);
        tsum0 += (dsub0 && mloc == l31) ? 0.0f : e0;
        tsum1 += (dsub1 && mloc == l31) ? 0.0f : e1;
      }
    } else {
#pragma unroll
      for (int r = 0; r < 16; ++r) {
        tsum0 += __builtin_amdgcn_exp2f(acc0[r]);
        tsum1 += __builtin_amdgcn_exp2f(acc1[r]);
      }
    }
    const float tsum = tsum0 + tsum1;
    gsum += (rtt == ctt) ? tsum : (tsum + tsum);  // off-diag mirrored x2

    __builtin_amdgcn_s_barrier();  // buf reads done before its re-stage
    rtt = nrt;
    ctt = nct;
  }

  // ---- strip phase: last 32 tiles as 128 column-strips (128x32), one per
  //      block with c%4==0; waves 0-3 each run one 32x32 chain, frags
  //      loaded global->reg (L2-resident, tiny volume). ----
  if ((c & 3) == 0 && wid < 4) {
    const int k = c >> 2;            // 0..127
    const int e = 2048 + (k >> 2);   // tile index 2048..2079
    const int s = k & 3;             // column strip within the tile
    int rt2, ct2;
    triDecode(e, rt2, ct2);
    const uint4* ap =
        (const uint4*)(zh + (size_t)((rt2 << 7) + 32 * wid + l31) * DIM);
    const uint4* bp =
        (const uint4*)(zh + (size_t)((ct2 << 7) + 32 * s + l31) * DIM);
    uint4 af[8], bf[8];
#pragma unroll
    for (int ks = 0; ks < 8; ++ks) {
      af[ks] = ap[2 * ks + lhi];
      bf[ks] = bp[2 * ks + lhi];
    }
    f32x16 acc;
#pragma unroll
    for (int r = 0; r < 16; ++r) acc[r] = -L2E;
#pragma unroll
    for (int ks = 0; ks < 8; ++ks)
      acc = __builtin_amdgcn_mfma_f32_32x32x16_f16(
          __builtin_bit_cast(f16x8, af[ks]), __builtin_bit_cast(f16x8, bf[ks]),
          acc, 0, 0, 0);
    float tsum = 0.0f;
    const bool dsub = (rt2 == ct2) && (wid == s);  // wave-uniform
    if (dsub) {
#pragma unroll
      for (int r = 0; r < 16; ++r) {
        const float e2 = __builtin_amdgcn_exp2f(acc[r]);
        const int mloc = (r & 3) + 4 * lhi + 8 * (r >> 2);
        tsum += (mloc != l31) ? e2 : 0.0f;
      }
    } else {
#pragma unroll
      for (int r = 0; r < 16; ++r) tsum += __builtin_amdgcn_exp2f(acc[r]);
    }
    gsum += (rt2 == ct2) ? tsum : (tsum + tsum);
  }

  // ---- per-block reduction -> pairP[c] ----
#pragma unroll
  for (int off = 32; off; off >>= 1) gsum += __shfl_xor(gsum, off);
  if (lane == 0) wsum[wid] = gsum;
  __syncthreads();
  if (tid == 0) {
    float s = 0.0f;
#pragma unroll
    for (int q = 0; q < 8; ++q) s += wsum[q];
    pairP[c] = s;
  }
}

// ---------------------------------------------------------------------------
// Kernel 3: single-block fused reduce + assemble scalar (deterministic
// fixed-order tree). star_neg = g + EPS exactly, so
// star_mean = negSum/(N(N-1)) + EPS.
// ---------------------------------------------------------------------------
__global__ void fmicl_reduce(const float* __restrict__ pairP,
                             const float* __restrict__ sposB,
                             float* __restrict__ out) {
  const int t = threadIdx.x;  // 1024 threads = 16 waves
  double nsum = (t < NBLK) ? (double)pairP[t] : 0.0;
  double psum = (t < 256) ? (double)sposB[t] : 0.0;
#pragma unroll
  for (int off = 32; off; off >>= 1) {
    nsum += __shfl_xor(nsum, off);
    psum += __shfl_xor(psum, off);
  }
  __shared__ double ls[2][16];
  const int lane = t & 63;
  const int wid = t >> 6;
  if (lane == 0) {
    ls[0][wid] = nsum;
    ls[1][wid] = psum;
  }
  __syncthreads();
  if (t == 0) {
    double nn = 0.0, pp = 0.0;
#pragma unroll
    for (int q = 0; q < 16; ++q) {
      nn += ls[0][q];
      pp += ls[1][q];
    }
    const double pos_mean = pp / (double)NROWS;
    const double star_mean = nn / ((double)NROWS * (double)(NROWS - 1)) + 1e-8;
    out[0] = (float)(-pos_mean + 1.5 * star_mean);
  }
}

extern "C" void kernel_launch(void* const* d_in, const int* in_sizes, int n_in,
                              void* d_out, int out_size, void* d_ws,
                              size_t ws_size, hipStream_t stream) {
  const float* z1 = (const float*)d_in[0];
  const float* z2 = (const float*)d_in[1];
  float* out = (float*)d_out;
  char* ws = (char*)d_ws;

  // ws layout (every slot rewritten every call; no memset needed):
  //   [0)     pairP float[512]    (2048 B, pad to 4096)
  //   [4096)  sposB float[256]    (1024 B)
  //   [6144)  zh    f16[8192*128] (2 MiB, 16B-aligned)
  float* pairP = (float*)(ws + 0);
  float* sposB = (float*)(ws + 4096);
  _Float16* zh = (_Float16*)(ws + 6144);

  fmicl_normalize<<<256, 1024, 0, stream>>>(z1, z2, zh, sposB);
  fmicl_pairwise<<<NBLK, 512, 0, stream>>>(zh, pairP);
  fmicl_reduce<<<1, 1024, 0, stream>>>(pairP, sposB, out);
}

// Round 19
// 28.839 us; speedup vs baseline: 1.0798x; 1.0798x over previous
//
#include <hip/hip_runtime.h>

#define NROWS 8192
#define DIM 128
#define NT 64      // 128x128 tiles per side
#define NBLK 512   // pairwise blocks; block c owns 4(+1) consecutive tiles

typedef _Float16 f16x8 __attribute__((ext_vector_type(8)));
typedef _Float16 f16x4 __attribute__((ext_vector_type(4)));
typedef float f32x16 __attribute__((ext_vector_type(16)));

#define L2E 1.4426950408889634f      // log2(e)
#define SQRTL2E 1.2011224087864498f  // sqrt(log2(e))

#define AS1(p) ((const __attribute__((address_space(1))) void*)(p))
#define AS3(p) ((__attribute__((address_space(3))) void*)(p))

// ---------------------------------------------------------------------------
// Kernel 1: per-row L2 normalize (fp32, as reference), float4-vectorized
// (R16-verified). zh is PRE-SCALED by sqrt(log2e) so the Gram MFMA produces
// L2E*dot directly; with acc initialized to -L2E the epilogue needs no fma
// (R17-verified). Each wave: two rows (lanes 0-31 / 32-63), 16 B/lane.
// 256 blocks x 32 rows. sposB: per-block partial of the positive term.
// No atomics.
// ---------------------------------------------------------------------------
__global__ __launch_bounds__(1024) void fmicl_normalize(
    const float* __restrict__ z1, const float* __restrict__ z2,
    _Float16* __restrict__ zh, float* __restrict__ sposB) {
  const int wid = threadIdx.x >> 6;
  const int lane = threadIdx.x & 63;
  const int half = lane >> 5;   // 0/1: which of the wave's two rows
  const int li = lane & 31;     // position within the row (x float4)
  const int row = blockIdx.x * 32 + wid * 2 + half;

  const float4 a = ((const float4*)(z1 + (size_t)row * DIM))[li];
  const float4 b = ((const float4*)(z2 + (size_t)row * DIM))[li];
  float s1 = a.x * a.x + a.y * a.y + a.z * a.z + a.w * a.w;
  float s2 = b.x * b.x + b.y * b.y + b.z * b.z + b.w * b.w;
#pragma unroll
  for (int off = 16; off; off >>= 1) {  // within-half reduction (32 lanes)
    s1 += __shfl_xor(s1, off);
    s2 += __shfl_xor(s2, off);
  }
  const float inv1 = 1.0f / fmaxf(sqrtf(s1), 1e-12f);
  const float inv2 = 1.0f / fmaxf(sqrtf(s2), 1e-12f);
  const float n1x = a.x * inv1, n1y = a.y * inv1, n1z = a.z * inv1,
              n1w = a.w * inv1;
  const float dx = n1x - b.x * inv2, dy = n1y - b.y * inv2,
              dz = n1z - b.z * inv2, dw = n1w - b.w * inv2;
  float dp = dx * dx + dy * dy + dz * dz + dw * dw;
#pragma unroll
  for (int off = 16; off; off >>= 1) dp += __shfl_xor(dp, off);

  f16x4 h;  // store n1 * sqrt(log2e): Gram dot comes out pre-multiplied
  h.x = (_Float16)(n1x * SQRTL2E);
  h.y = (_Float16)(n1y * SQRTL2E);
  h.z = (_Float16)(n1z * SQRTL2E);
  h.w = (_Float16)(n1w * SQRTL2E);
  *(f16x4*)(zh + (size_t)row * DIM + 4 * li) = h;

  __shared__ float sposL[32];
  if (li == 0)
    sposL[wid * 2 + half] = logf(expf(-0.5f * dp) + 1e-8f) + 1.0f;  // f'(g_pos)
  __syncthreads();
  if (threadIdx.x == 0) {
    float s = 0.0f;
#pragma unroll
    for (int k = 0; k < 32; ++k) s += sposL[k];
    sposB[blockIdx.x] = s;
  }
}

// ---------------------------------------------------------------------------
// Stage one 128-row B panel (32 KiB) into LDS via global_load_lds width=16.
// LDS dest linear; global source pre-swizzled (granule col ^= row&15);
// read side applies the same XOR (involution; rounds 3-17 verified,
// 0 bank conflicts). 4 VMEM instructions per wave.
// ---------------------------------------------------------------------------
__device__ __forceinline__ void stageB(const _Float16* __restrict__ zh,
                                       _Float16* buf, int ct, int wid,
                                       int lane) {
  const _Float16* base = zh + ((size_t)ct << 7) * DIM;
#pragma unroll
  for (int it = 0; it < 4; ++it) {
    const int P = it * 8 + wid;          // wave-uniform 4-row group 0..31
    const int R = P * 4 + (lane >> 4);   // row 0..127
    const int cs = (lane & 15) ^ (R & 15);
    __builtin_amdgcn_global_load_lds(AS1(base + (size_t)R * DIM + cs * 8),
                                     AS3(buf + P * 512), 16, 0, 0);
  }
}

// ---------------------------------------------------------------------------
// Kernel 2: champion pairwise (R17, best of 18 measured variants: 28.87 us).
// 512 blocks x 512 threads (8 waves, 4M x 2N); wave = 32 A-rows in regs x
// 64 B-cols from LDS (2 ds_read_b128 -> 2 MFMA per K-step). B double-
// buffered (2 x 32 KiB); next tile staged before compute with counted
// s_waitcnt vmcnt(4) (T4). acc initialized to -L2E (MFMA D = A*B + C) and
// zh pre-scaled by sqrt(L2E) -> acc_final = L2E*dot - L2E; epilogue is
// gsum += exp2(acc[r]): 2 ops/pair. Diagonal masked; off-diag tiles x2.
// Block c owns tiles [4c+nx, +len) of the flat triangular list (len=5 when
// c%16==0). XCD swizzle (bid&7)*64+bid>>3 (bijective, 260 tiles/XCD).
// No atomics.
// ---------------------------------------------------------------------------
__global__ __launch_bounds__(512, 4) void fmicl_pairwise(
    const _Float16* __restrict__ zh, float* __restrict__ pairP) {
  __shared__ _Float16 B0[128 * DIM];  // 32 KiB
  __shared__ _Float16 B1[128 * DIM];  // 32 KiB
  __shared__ float wsum[8];

  const int tid = threadIdx.x;
  const int lane = tid & 63;
  const int wid = tid >> 6;
  const int l31 = lane & 31;
  const int lhi = lane >> 5;
  const int m = wid >> 1;  // 0..3: 32-row block of the band
  const int n = wid & 1;   // 0..1: 64-col half of the tile

  // XCD-chunked swizzle (512 = 8*64, bijective; 260 tiles per XCD)
  const int c = (blockIdx.x & 7) * 64 + (blockIdx.x >> 3);
  const int nx = (c + 15) >> 4;  // len-5 chunks before c
  const int base = 4 * c + nx;
  const int len = 4 + ((c & 15) == 0 ? 1 : 0);

  // ---- decode base -> (rt, ct); C(r) = r*NT - r(r-1)/2 ----
  int rt = (int)(64.5f - sqrtf(64.5f * 64.5f - 2.0f * (float)base));
  if (rt < 0) rt = 0;
  while (rt > 0 && (rt * NT - (rt * (rt - 1)) / 2) > base) --rt;
  while (((rt + 1) * NT - ((rt + 1) * rt) / 2) <= base) ++rt;
  int ctt = rt + (base - (rt * NT - (rt * (rt - 1)) / 2));
  int rtt = rt;

  stageB(zh, B0, ctt, wid, lane);  // prologue stage of tile 0

  uint4 areg[8];
  int cur_rt = -1;
  float gsum = 0.0f;

#pragma unroll 1
  for (int t = 0; t < len; ++t) {
    // ---- A-regs: reload only on band crossing ----
    if (rtt != cur_rt) {
      cur_rt = rtt;
      const uint4* ar =
          (const uint4*)(zh + (size_t)((rtt << 7) + m * 32 + l31) * DIM);
#pragma unroll
      for (int ks = 0; ks < 8; ++ks) areg[ks] = ar[2 * ks + lhi];
    }
    // ---- next tile coords; issue its stage before computing this one ----
    int nrt = rtt, nct = ctt + 1;
    if (nct == NT) { ++nrt; nct = nrt; }
    if (t + 1 < len) {
      stageB(zh, (t & 1) ? B0 : B1, nct, wid, lane);
      // all but the newest 4 loads (= next tile's stage) complete: current
      // B-panel + any A-reload are in. Next stage flies across the barrier.
      asm volatile("s_waitcnt vmcnt(4)" ::: "memory");
    } else {
      asm volatile("s_waitcnt vmcnt(0)" ::: "memory");
    }
    __builtin_amdgcn_s_barrier();
    __builtin_amdgcn_sched_barrier(0);

    // ---- compute: 8 K-steps, 2 B-reads -> 2 MFMA (A from registers).
    //      acc starts at -L2E: final acc[r] = L2E*dot - L2E (C-input fusion)
    const uint4* B4 = (const uint4*)((t & 1) ? B1 : B0);
    const int rb0 = n * 64 + l31;
    const int rb1 = n * 64 + 32 + l31;
    f32x16 acc0, acc1;
#pragma unroll
    for (int r = 0; r < 16; ++r) {
      acc0[r] = -L2E;
      acc1[r] = -L2E;
    }
#pragma unroll
    for (int ks = 0; ks < 8; ++ks) {
      const int kg = 2 * ks + lhi;
      const uint4 vb0 = B4[rb0 * 16 + (kg ^ (rb0 & 15))];
      const uint4 vb1 = B4[rb1 * 16 + (kg ^ (rb1 & 15))];
      const f16x8 af = __builtin_bit_cast(f16x8, areg[ks]);
      acc0 = __builtin_amdgcn_mfma_f32_32x32x16_f16(
          af, __builtin_bit_cast(f16x8, vb0), acc0, 0, 0, 0);
      acc1 = __builtin_amdgcn_mfma_f32_32x32x16_f16(
          af, __builtin_bit_cast(f16x8, vb1), acc1, 0, 0, 0);
    }

    // ---- epilogue: g = exp2(acc[r]) == exp(dot-1) == exp(-d2/2) ----
    // C/D layout (32x32): col=lane&31, row=(reg&3)+8*(reg>>2)+4*(lane>>5)
    float tsum0 = 0.0f, tsum1 = 0.0f;
    const bool dsub0 = (rtt == ctt) && (m == 2 * n);      // chain-0 diag
    const bool dsub1 = (rtt == ctt) && (m == 2 * n + 1);  // chain-1 diag
    if (dsub0 || dsub1) {
#pragma unroll
      for (int r = 0; r < 16; ++r) {
        const float e0 = __builtin_amdgcn_exp2f(acc0[r]);
        const float e1 = __builtin_amdgcn_exp2f(acc1[r]);
        const int mloc = (r & 3) + 4 * lhi + 8 * (r >> 2);
        tsum0 += (dsub0 && mloc == l31) ? 0.0f : e0;
        tsum1 += (dsub1 && mloc == l31) ? 0.0f : e1;
      }
    } else {
#pragma unroll
      for (int r = 0; r < 16; ++r) {
        tsum0 += __builtin_amdgcn_exp2f(acc0[r]);
        tsum1 += __builtin_amdgcn_exp2f(acc1[r]);
      }
    }
    const float tsum = tsum0 + tsum1;
    gsum += (rtt == ctt) ? tsum : (tsum + tsum);  // off-diag mirrored x2

    __builtin_amdgcn_s_barrier();  // buf reads done before its re-stage
    rtt = nrt;
    ctt = nct;
  }

  // ---- per-block reduction -> pairP[c] ----
#pragma unroll
  for (int off = 32; off; off >>= 1) gsum += __shfl_xor(gsum, off);
  if (lane == 0) wsum[wid] = gsum;
  __syncthreads();
  if (tid == 0) {
    float s = 0.0f;
#pragma unroll
    for (int q = 0; q < 8; ++q) s += wsum[q];
    pairP[c] = s;
  }
}

// ---------------------------------------------------------------------------
// Kernel 3: single-block fused reduce + assemble scalar (deterministic
// fixed-order tree). star_neg = g + EPS exactly, so
// star_mean = negSum/(N(N-1)) + EPS.
// ---------------------------------------------------------------------------
__global__ void fmicl_reduce(const float* __restrict__ pairP,
                             const float* __restrict__ sposB,
                             float* __restrict__ out) {
  const int t = threadIdx.x;  // 1024 threads = 16 waves
  double nsum = (t < NBLK) ? (double)pairP[t] : 0.0;
  double psum = (t < 256) ? (double)sposB[t] : 0.0;
#pragma unroll
  for (int off = 32; off; off >>= 1) {
    nsum += __shfl_xor(nsum, off);
    psum += __shfl_xor(psum, off);
  }
  __shared__ double ls[2][16];
  const int lane = t & 63;
  const int wid = t >> 6;
  if (lane == 0) {
    ls[0][wid] = nsum;
    ls[1][wid] = psum;
  }
  __syncthreads();
  if (t == 0) {
    double nn = 0.0, pp = 0.0;
#pragma unroll
    for (int q = 0; q < 16; ++q) {
      nn += ls[0][q];
      pp += ls[1][q];
    }
    const double pos_mean = pp / (double)NROWS;
    const double star_mean = nn / ((double)NROWS * (double)(NROWS - 1)) + 1e-8;
    out[0] = (float)(-pos_mean + 1.5 * star_mean);
  }
}

extern "C" void kernel_launch(void* const* d_in, const int* in_sizes, int n_in,
                              void* d_out, int out_size, void* d_ws,
                              size_t ws_size, hipStream_t stream) {
  const float* z1 = (const float*)d_in[0];
  const float* z2 = (const float*)d_in[1];
  float* out = (float*)d_out;
  char* ws = (char*)d_ws;

  // ws layout (every slot rewritten every call; no memset needed):
  //   [0)     pairP float[512]    (2048 B, pad to 4096)
  //   [4096)  sposB float[256]    (1024 B)
  //   [6144)  zh    f16[8192*128] (2 MiB, 16B-aligned)
  float* pairP = (float*)(ws + 0);
  float* sposB = (float*)(ws + 4096);
  _Float16* zh = (_Float16*)(ws + 6144);

  fmicl_normalize<<<256, 1024, 0, stream>>>(z1, z2, zh, sposB);
  fmicl_pairwise<<<NBLK, 512, 0, stream>>>(zh, pairP);
  fmicl_reduce<<<1, 1024, 0, stream>>>(pairP, sposB, out);
}